// Round 14
// baseline (131.361 us; speedup 1.0000x reference)
//
#include <hip/hip_runtime.h>
#include <hip/hip_bf16.h>

typedef float  f32x4  __attribute__((ext_vector_type(4)));
typedef short  bf16x8 __attribute__((ext_vector_type(8)));

#define NT      16384            // BATCH*SEQ tokens
#define NBLOCK  512              // 256-thr blocks; (256,2) + 80KB LDS
#define TPS     (NT / NBLOCK)    // 32 tokens per block, CONTIGUOUS chunk

__device__ __forceinline__ short f2bf(float x) {
  return (short)__builtin_bit_cast(unsigned short, __float2bfloat16(x));
}
__device__ __forceinline__ unsigned packbf2(float a, float b) {
  return (unsigned)(unsigned short)f2bf(a) | ((unsigned)(unsigned short)f2bf(b) << 16);
}

__device__ __forceinline__ void gload16(const float* gp, float* lp) {
  __builtin_amdgcn_global_load_lds((const __attribute__((address_space(1))) void*)gp,
                                   (__attribute__((address_space(3))) void*)lp,
                                   16, 0, 0);
}
__device__ __forceinline__ unsigned ldsaddr(const void* p) {
  return (unsigned)(uintptr_t)(const __attribute__((address_space(3))) void*)p;
}

// Team-stage one token's X (16KB): wave w stages chunks q=4w..4w+3 (4 gloads/wave).
// Global-side XOR swizzle (16B chunks, chunk ^= row&7): proven 0 conflicts.
__device__ __forceinline__ void stageQW(float* XB, const float* gbase, int w, int lane) {
#pragma unroll
  for (int qq = 0; qq < 4; ++qq) {
    const int q = w * 4 + qq;
    const int i = q * 4 + (lane >> 4);
    const float* gp = gbase + i * 64 + (((lane & 15) ^ (i & 7)) << 2);
    gload16(gp, XB + q * 256);
  }
}

__global__ __launch_bounds__(256, 2)   // 2 waves/SIMD occupancy target; the
                                       // cooperative split fits the 128-VGPR cap
                                       // spill-free (R12: clean FETCH/WRITE).
void kron_kernel(const float* __restrict__ x,
                 const float* __restrict__ A,
                 const float* __restrict__ Bm,
                 const float* __restrict__ bias,
                 float* __restrict__ out) {
  __shared__ float  xb[2][4096];            // 32KB X double-buffer (one token/team)
  __shared__ bf16x8 AT[1024];               // 16KB [s*8+ot*2+c][lane], sigma2 baked
  __shared__ bf16x8 BT[1024];               // 16KB [s*8+pt*2+jc][lane], sigma1
  __shared__ unsigned long long Ul[2048];   // 16KB U exchange: [s][pt][g][l15][slot0..3]

  const int tid  = threadIdx.x;
  const int lane = tid & 63;
  const int w    = tid >> 6;               // wave role: stage1 it=w, stage2 pt=w
  const int g    = lane >> 4;
  const int l15  = lane & 15;

  // ---- mapping change (the experiment): contiguous 32-token chunk per block,
  // XCD-chunked bijective block swizzle (512 blocks = 8 XCDs x 64 contiguous).
  // Every stream advances LINEARLY through x and out (DRAM-row / L2 locality);
  // XCD x owns one contiguous 32MB region.
  const int swz = ((blockIdx.x & 7) << 6) | (blockIdx.x >> 3);
  const size_t tokBase = (size_t)swz * TPS;

  // ---- one-time: operand tables (4 rows per wave per table) ----
#pragma unroll
  for (int t = 0; t < 4; ++t) {                  // A: idx = s*8 + ot*2 + c
    const int idx = w * 4 + t;
    const int s = idx >> 3, ot = (idx & 7) >> 1, c = idx & 1;
    const int o = ot * 16 + l15;
    bf16x8 v;
#pragma unroll
    for (int e = 0; e < 8; ++e) {
      const int i = c * 32 + 4 * g + (e & 3) + 16 * (e >> 2);   // sigma2
      v[e] = f2bf(A[s * 4096 + o * 64 + i]);
    }
    AT[idx * 64 + lane] = v;
  }
#pragma unroll
  for (int t = 0; t < 4; ++t) {                  // B: idx = s*8 + pt*2 + jc
    const int idx = w * 4 + t;
    const int s = idx >> 3, pt = (idx & 7) >> 1, jc = idx & 1;
    const int p = pt * 16 + l15;
    bf16x8 v;
#pragma unroll
    for (int e = 0; e < 8; ++e)
      v[e] = f2bf(Bm[s * 4096 + p * 64 + (jc * 32 + 8 * g + e)]); // sigma1
    BT[idx * 64 + lane] = v;
  }

  // ---- bias slice (pt=w): 4 x f32x4 = 16 VGPR ----
  f32x4 bv[4];
#pragma unroll
  for (int ot = 0; ot < 4; ++ot)
    bv[ot] = *(const f32x4*)(bias + (ot * 16 + l15) * 64 + w * 16 + 4 * g);

  __syncthreads();   // tables visible; no gloads in flight yet, drain is free

  // ---- prologue: stage tokens 0,1 of this block's chunk ----
  stageQW(&xb[0][0], x + (tokBase << 12), w, lane);
  stageQW(&xb[1][0], x + ((tokBase + 1) << 12), w, lane);
  asm volatile("s_waitcnt vmcnt(4)" ::: "memory");   // own X0 chunk done
  __builtin_amdgcn_s_barrier();                      // team X0 complete

  const unsigned wsw = (unsigned)(2 * ((l15 >> 2) & 1));   // U slot swizzle bit

  for (int k = 0; k < TPS; ++k) {
    // ---- 1. xf for it=w from xb[k&1] (asm ds_read, invisible to waitcnt pass) ----
    const unsigned ba   = ldsaddr(&xb[k & 1][0]);
    const unsigned base = ba + (unsigned)(w * 16 + l15) * 256u;
    const unsigned m    = (unsigned)(l15 & 7);
    f32x4 r0[2], r1[2];
#pragma unroll
    for (int jc = 0; jc < 2; ++jc) {
      const unsigned c0 = (unsigned)(8 * jc + 2 * g);
      asm volatile("ds_read_b128 %0, %1" : "=v"(r0[jc]) : "v"(base + ((c0 ^ m) << 4)) : "memory");
      asm volatile("ds_read_b128 %0, %1" : "=v"(r1[jc]) : "v"(base + (((c0 + 1u) ^ m) << 4)) : "memory");
    }
    asm volatile("s_waitcnt lgkmcnt(0)" ::: "memory");
    __builtin_amdgcn_sched_barrier(0);

    bf16x8 xf[2];
#pragma unroll
    for (int jc = 0; jc < 2; ++jc) {
      bf16x8 t;
      t[0]=f2bf(r0[jc][0]); t[1]=f2bf(r0[jc][1]); t[2]=f2bf(r0[jc][2]); t[3]=f2bf(r0[jc][3]);
      t[4]=f2bf(r1[jc][0]); t[5]=f2bf(r1[jc][1]); t[6]=f2bf(r1[jc][2]); t[7]=f2bf(r1[jc][3]);
      xf[jc] = t;
    }

    // ---- 2. stage 1 (it=w, all pt, both s): U tiles -> LDS exchange ----
#pragma unroll
    for (int s = 0; s < 2; ++s) {
#pragma unroll
      for (int pt = 0; pt < 4; ++pt) {
        f32x4 a1 = (f32x4){0.f, 0.f, 0.f, 0.f};
#pragma unroll
        for (int jc = 0; jc < 2; ++jc)
          a1 = __builtin_amdgcn_mfma_f32_16x16x32_bf16(
              xf[jc], BT[(s * 8 + pt * 2 + jc) * 64 + lane], a1, 0, 0, 0);
        // lane holds U[w*16+4g+r][pt*16+l15], r=0..3 -> one 8B slot
        const unsigned lo = packbf2(a1[0], a1[1]);
        const unsigned hi = packbf2(a1[2], a1[3]);
        Ul[((((s * 4 + pt) * 4 + g) * 16 + l15) << 2) + ((unsigned)w ^ wsw)] =
            ((unsigned long long)hi << 32) | lo;
      }
    }

    // ---- 3. barrier 1: U visible (lgkmcnt only; vmcnt prefetch stays in flight) ----
    asm volatile("s_waitcnt lgkmcnt(0)" ::: "memory");
    __builtin_amdgcn_sched_barrier(0);
    __builtin_amdgcn_s_barrier();

    // ---- 4. stage X(k+2) into the buffer just consumed (all xf reads done) ----
    if (k + 2 < TPS)
      stageQW(&xb[k & 1][0], x + ((tokBase + k + 2) << 12), w, lane);

    // ---- 5. stage 2 (pt=w, all ot, both s) ----
    f32x4 acc[4];
#pragma unroll
    for (int ot = 0; ot < 4; ++ot) acc[ot] = bv[ot];
#pragma unroll
    for (int s = 0; s < 2; ++s) {
      bf16x8 uf[2];
#pragma unroll
      for (int c = 0; c < 2; ++c) {
        const unsigned q2 = (unsigned)((l15 >> 2) & 1);
        uf[c] = *reinterpret_cast<const bf16x8*>(
            &Ul[((((s * 4 + w) * 4 + g) * 16 + l15) << 2) + 2u * ((unsigned)c ^ q2)]);
      }
#pragma unroll
      for (int ot = 0; ot < 4; ++ot)
#pragma unroll
        for (int c = 0; c < 2; ++c)
          acc[ot] = __builtin_amdgcn_mfma_f32_16x16x32_bf16(
              uf[c], AT[(s * 8 + ot * 2 + c) * 64 + lane], acc[ot], 0, 0, 0);
    }

    // ---- 6. store (pt=w slice; bias pre-folded) ----
    float* ob = out + ((tokBase + k) << 12);
#pragma unroll
    for (int ot = 0; ot < 4; ++ot)
      *(f32x4*)(ob + (ot * 16 + l15) * 64 + w * 16 + 4 * g) = acc[ot];

    // ---- 7. barrier 2: counted vmcnt. Steady queue (old->new):
    // [gl(k+1) 4][st(k-1) 4][gl(k+2) 4][st(k) 4] -> vmcnt(8) retires gl(k+1)+st(k-1);
    // X(k+1) ready before token k+1; prefetch gl(k+2) stays in flight. Tail
    // verified: at k=TPS-2 outstanding=[gl(TPS-1) 4][st 4][st 4]=12 -> retires gl.
    // lgkmcnt(0): uf reads serviced before next token's U overwrite.
    asm volatile("s_waitcnt vmcnt(8) lgkmcnt(0)" ::: "memory");
    __builtin_amdgcn_sched_barrier(0);
    __builtin_amdgcn_s_barrier();
  }
}

extern "C" void kernel_launch(void* const* d_in, const int* in_sizes, int n_in,
                              void* d_out, int out_size, void* d_ws, size_t ws_size,
                              hipStream_t stream) {
  const float* x    = (const float*)d_in[0];
  const float* A    = (const float*)d_in[1];
  const float* B    = (const float*)d_in[2];
  const float* bias = (const float*)d_in[3];
  float* out        = (float*)d_out;
  kron_kernel<<<dim3(NBLOCK), dim3(256), 0, stream>>>(x, A, B, bias, out);
}

// Round 15
// 100.516 us; speedup vs baseline: 1.3069x; 1.3069x over previous
//
#include <hip/hip_runtime.h>
#include <hip/hip_bf16.h>

typedef float  f32x4  __attribute__((ext_vector_type(4)));
typedef short  bf16x8 __attribute__((ext_vector_type(8)));

#define NT      16384            // BATCH*SEQ tokens
#define NBLOCK  256              // 512-thr blocks; 112KB LDS -> exactly 1 block/CU
#define TPS     (NT / NBLOCK)    // 64 tokens per block, strided by NBLOCK (proven best)

__device__ __forceinline__ short f2bf(float x) {
  return (short)__builtin_bit_cast(unsigned short, __float2bfloat16(x));
}
__device__ __forceinline__ unsigned packbf2(float a, float b) {
  return (unsigned)(unsigned short)f2bf(a) | ((unsigned)(unsigned short)f2bf(b) << 16);
}

__device__ __forceinline__ void gload16(const float* gp, float* lp) {
  __builtin_amdgcn_global_load_lds((const __attribute__((address_space(1))) void*)gp,
                                   (__attribute__((address_space(3))) void*)lp,
                                   16, 0, 0);
}
__device__ __forceinline__ unsigned ldsaddr(const void* p) {
  return (unsigned)(uintptr_t)(const __attribute__((address_space(3))) void*)p;
}

// Producer wave j stages chunks q=4j..4j+3 of one token's X (4 x 1KB gloads).
// Global-side XOR swizzle (16B chunks, chunk ^= row&7): proven 0 conflicts.
__device__ __forceinline__ void stageQW(float* XB, const float* gbase, int j, int lane) {
#pragma unroll
  for (int qq = 0; qq < 4; ++qq) {
    const int q = j * 4 + qq;
    const int i = q * 4 + (lane >> 4);
    const float* gp = gbase + i * 64 + (((lane & 15) ^ (i & 7)) << 2);
    gload16(gp, XB + q * 256);
  }
}

__global__ __launch_bounds__(512, 1)
void kron_kernel(const float* __restrict__ x,
                 const float* __restrict__ A,
                 const float* __restrict__ Bm,
                 const float* __restrict__ bias,
                 float* __restrict__ out) {
  // Producer/consumer wave specialization: waves 0-3 compute (R12 cooperative
  // split, NO vmcnt waits ever), waves 4-7 stream X through a 4-deep ring and
  // absorb all vmcnt waits. Decouples compute stalls from memory-queue feed.
  __shared__ float  xb[4][4096];            // 64KB X ring (4 tokens)
  __shared__ bf16x8 AT[1024];               // 16KB [s*8+ot*2+c][lane], sigma2 baked
  __shared__ bf16x8 BT[1024];               // 16KB [s*8+pt*2+jc][lane], sigma1
  __shared__ unsigned long long Ul[2048];   // 16KB U exchange

  const int tid  = threadIdx.x;
  const int lane = tid & 63;
  const int w    = tid >> 6;               // 0-3 consumer, 4-7 producer
  const int j    = w & 3;
  const int g    = lane >> 4;
  const int l15  = lane & 15;
  const int blk  = blockIdx.x;
  const bool consumer = (w < 4);

  // ---- one-time: operand tables + bias (consumer waves only; 4 rows/table) ----
  f32x4 bv[4];
  if (consumer) {
#pragma unroll
    for (int t = 0; t < 4; ++t) {                  // A: idx = s*8 + ot*2 + c
      const int idx = j * 4 + t;
      const int s = idx >> 3, ot = (idx & 7) >> 1, c = idx & 1;
      const int o = ot * 16 + l15;
      bf16x8 v;
#pragma unroll
      for (int e = 0; e < 8; ++e) {
        const int i = c * 32 + 4 * g + (e & 3) + 16 * (e >> 2);   // sigma2
        v[e] = f2bf(A[s * 4096 + o * 64 + i]);
      }
      AT[idx * 64 + lane] = v;
    }
#pragma unroll
    for (int t = 0; t < 4; ++t) {                  // B: idx = s*8 + pt*2 + jc
      const int idx = j * 4 + t;
      const int s = idx >> 3, pt = (idx & 7) >> 1, jc = idx & 1;
      const int p = pt * 16 + l15;
      bf16x8 v;
#pragma unroll
      for (int e = 0; e < 8; ++e)
        v[e] = f2bf(Bm[s * 4096 + p * 64 + (jc * 32 + 8 * g + e)]); // sigma1
      BT[idx * 64 + lane] = v;
    }
#pragma unroll
    for (int ot = 0; ot < 4; ++ot)
      bv[ot] = *(const f32x4*)(bias + (ot * 16 + l15) * 64 + j * 16 + 4 * g);
  }
  __syncthreads();   // tables visible; full drain is free here (no gloads yet)

  // ---- prologue: producers stage tokens 0,1,2 into ring slots 0,1,2 ----
  if (!consumer) {
    stageQW(&xb[0][0], x + ((size_t)blk << 12),                j, lane);
    stageQW(&xb[1][0], x + ((size_t)(blk + NBLOCK) << 12),     j, lane);
    stageQW(&xb[2][0], x + ((size_t)(blk + 2 * NBLOCK) << 12), j, lane);
    asm volatile("s_waitcnt vmcnt(8)" ::: "memory");   // token 0 resident
  }
  __builtin_amdgcn_s_barrier();

  const unsigned wsw = (unsigned)(2 * ((l15 >> 2) & 1));   // U slot swizzle bit

  for (int k = 0; k < TPS; ++k) {
    if (consumer) {
      // ---- 1. xf for it=j from ring[k&3] (asm ds_read, waitcnt-invisible) ----
      const unsigned ba   = ldsaddr(&xb[k & 3][0]);
      const unsigned base = ba + (unsigned)(j * 16 + l15) * 256u;
      const unsigned m    = (unsigned)(l15 & 7);
      f32x4 r0[2], r1[2];
#pragma unroll
      for (int jc = 0; jc < 2; ++jc) {
        const unsigned c0 = (unsigned)(8 * jc + 2 * g);
        asm volatile("ds_read_b128 %0, %1" : "=v"(r0[jc]) : "v"(base + ((c0 ^ m) << 4)) : "memory");
        asm volatile("ds_read_b128 %0, %1" : "=v"(r1[jc]) : "v"(base + (((c0 + 1u) ^ m) << 4)) : "memory");
      }
      asm volatile("s_waitcnt lgkmcnt(0)" ::: "memory");
      __builtin_amdgcn_sched_barrier(0);

      bf16x8 xf[2];
#pragma unroll
      for (int jc = 0; jc < 2; ++jc) {
        bf16x8 t;
        t[0]=f2bf(r0[jc][0]); t[1]=f2bf(r0[jc][1]); t[2]=f2bf(r0[jc][2]); t[3]=f2bf(r0[jc][3]);
        t[4]=f2bf(r1[jc][0]); t[5]=f2bf(r1[jc][1]); t[6]=f2bf(r1[jc][2]); t[7]=f2bf(r1[jc][3]);
        xf[jc] = t;
      }

      // ---- 2. stage 1 (it=j, all pt, both s): U tiles -> LDS exchange ----
#pragma unroll
      for (int s = 0; s < 2; ++s) {
#pragma unroll
        for (int pt = 0; pt < 4; ++pt) {
          f32x4 a1 = (f32x4){0.f, 0.f, 0.f, 0.f};
#pragma unroll
          for (int jc = 0; jc < 2; ++jc)
            a1 = __builtin_amdgcn_mfma_f32_16x16x32_bf16(
                xf[jc], BT[(s * 8 + pt * 2 + jc) * 64 + lane], a1, 0, 0, 0);
          const unsigned lo = packbf2(a1[0], a1[1]);
          const unsigned hi = packbf2(a1[2], a1[3]);
          Ul[((((s * 4 + pt) * 4 + g) * 16 + l15) << 2) + ((unsigned)j ^ wsw)] =
              ((unsigned long long)hi << 32) | lo;
        }
      }
      asm volatile("s_waitcnt lgkmcnt(0)" ::: "memory");
      __builtin_amdgcn_sched_barrier(0);
    } else {
      // ---- producer phase A: issue token k+3 into the slot freed at k-1 ----
      if (k + 3 < TPS)
        stageQW(&xb[(k + 3) & 3][0],
                x + ((size_t)(blk + (k + 3) * NBLOCK) << 12), j, lane);
    }

    __builtin_amdgcn_s_barrier();   // barrier 1: U visible / ring write-safe

    if (consumer) {
      // ---- 3. stage 2 (pt=j, all ot, both s) + store ----
      f32x4 acc[4];
#pragma unroll
      for (int ot = 0; ot < 4; ++ot) acc[ot] = bv[ot];
#pragma unroll
      for (int s = 0; s < 2; ++s) {
        bf16x8 uf[2];
#pragma unroll
        for (int c = 0; c < 2; ++c) {
          const unsigned q2 = (unsigned)((l15 >> 2) & 1);
          uf[c] = *reinterpret_cast<const bf16x8*>(
              &Ul[((((s * 4 + j) * 4 + g) * 16 + l15) << 2) + 2u * ((unsigned)c ^ q2)]);
        }
#pragma unroll
        for (int ot = 0; ot < 4; ++ot)
#pragma unroll
          for (int c = 0; c < 2; ++c)
            acc[ot] = __builtin_amdgcn_mfma_f32_16x16x32_bf16(
                uf[c], AT[(s * 8 + ot * 2 + c) * 64 + lane], acc[ot], 0, 0, 0);
      }
      float* ob = out + ((size_t)(blk + k * NBLOCK) << 12);
#pragma unroll
      for (int ot = 0; ot < 4; ++ot)
        *(f32x4*)(ob + (ot * 16 + l15) * 64 + j * 16 + 4 * g) = acc[ot];
    } else {
      // ---- producer phase B: ensure token k+1 resident before barrier 2.
      // Outstanding per producer: tokens k+1..min(k+3,TPS-1), 4 gloads each.
      if (k < TPS - 3)       asm volatile("s_waitcnt vmcnt(8)" ::: "memory");
      else if (k == TPS - 3) asm volatile("s_waitcnt vmcnt(4)" ::: "memory");
      else                   asm volatile("s_waitcnt vmcnt(0)" ::: "memory");
    }

    __builtin_amdgcn_s_barrier();   // barrier 2: token k+1 ready, k consumed
  }
}

extern "C" void kernel_launch(void* const* d_in, const int* in_sizes, int n_in,
                              void* d_out, int out_size, void* d_ws, size_t ws_size,
                              hipStream_t stream) {
  const float* x    = (const float*)d_in[0];
  const float* A    = (const float*)d_in[1];
  const float* B    = (const float*)d_in[2];
  const float* bias = (const float*)d_in[3];
  float* out        = (float*)d_out;
  kron_kernel<<<dim3(NBLOCK), dim3(512), 0, stream>>>(x, A, B, bias, out);
}